// Round 2
// baseline (116.356 us; speedup 1.0000x reference)
//
#include <hip/hip_runtime.h>

// LogSparseAttention: B=2, L=S=2048, H=8, E=D=64, fp32.
// Mask (win_len=sub_len=2048, log_l=11):
//   l < 22  : causal prefix 0..l
//   l >= 22 : {l-10..l} U {l-10-2^j >= 0, j=0..10}  (<= 22 columns)
//
// R3: 4 rows/wave, 16 lanes/row, pure-DPP reduce.
// R4: XCD-aware swizzle.            R5/R6 (reverted): bf16 / mega-buffers.
// R7: 8-wave blocks for L1 locality.
// R8: head-per-XCD partitioning (NEUTRAL -> L2-footprint theory falsified).
// R9: MEASUREMENT PROBE, not an optimization. dur_us has never shown the
//     kernel's own share: every top-5 rocprof row is the harness's 256 MiB
//     workspace poison fill (~44 us). Kernel time is only bounded to
//     1..43 us, and the two candidate worlds (miss-queue-bound ~37 us vs
//     overhead-dominated ~10 us) demand opposite next steps. Probe: launch
//     the identical R8 kernel 3x back-to-back (idempotent, correctness-
//     safe). T_warm = (dur_new - 84.9)/2; if T >= ~15 us the kernel also
//     surfaces in top-5 with real PMC counters (VALUBusy, FETCH_SIZE,
//     occupancy) for the first time. Launches 2-3 run L3-warm, so the
//     cold/warm split additionally quantifies the first-touch HBM share
//     behind the cache-wiping fill.

constexpr int B = 2, L = 2048, S = 2048, H = 8, E = 64;
constexpr int LOGL = 11;                 // ceil(log2(2048))
constexpr int NG   = 6;                  // 6 groups x 4 col-slots = 24 >= 22
constexpr int WPB  = 8;                  // 8 waves = 8 consecutive bl rows
constexpr int NBLK = B * L * H / WPB;    // 4096 blocks (head = blockIdx & 7)

template<int CTRL>
__device__ __forceinline__ float dpp_add(float x) {
    int y = __builtin_amdgcn_update_dpp(0, __float_as_int(x), CTRL, 0xF, 0xF, true);
    return x + __int_as_float(y);
}

__global__ __launch_bounds__(WPB * 64)
void logsparse_attn(const float4* __restrict__ Q4,
                    const float4* __restrict__ K4,
                    const float4* __restrict__ V4,
                    float4* __restrict__ O4) {
    const int h    = blockIdx.x & 7;       // head == XCD (phys blk i -> XCD i%8)
    const int n    = blockIdx.x >> 3;      // 0..511: l-group, in-order per XCD
    const int lane = threadIdx.x & 63;
    const int w    = threadIdx.x >> 6;     // wave in block: 0..7
    const int bl   = n * WPB + w;          // b*L + l, 0..4095
    const int l    = bl & (L - 1);
    const int b    = bl >> 11;             // L = 2048
    const int r    = lane >> 4;            // column slot within group: 0..3
    const int g    = lane & 15;            // float4 slot within 64-float row

    // Per-lane active column for slot i = 4*grp + r (runtime r!).
    int  cols[NG];
    bool vld[NG];
    if (l < 2 * LOGL) {                    // full causal prefix
#pragma unroll
        for (int grp = 0; grp < NG; ++grp) {
            const int i = 4 * grp + r;
            vld[grp]  = (i <= l);
            cols[grp] = vld[grp] ? i : 0;
        }
    } else {
#pragma unroll
        for (int grp = 0; grp < NG; ++grp) {
            const int i  = 4 * grp + r;
            const int e  = i - LOGL;
            const int sh = (e < 0) ? 0 : e;            // avoid UB shift
            const int c  = (e < 0) ? (l - (LOGL - 1) + i)
                                   : (l - (LOGL - 1) - (1 << sh));
            vld[grp]  = (c >= 0);          // pad slots i=22,23: 2^11,2^12 -> c<0
            cols[grp] = vld[grp] ? c : 0;
        }
    }

    const int qidx   = (bl * H + h) * (E / 4) + g;
    const int kvbase = (b * S * H + h) * (E / 4) + g;
    constexpr int CS4 = H * (E / 4);       // 128 float4 between columns

    const float4 q = Q4[qidx];             // 256 B, row-duplicated (L1 bcast)

    // Dot partials: 6 loads x (4 cols x 256 B) = 16 lines each.
    float p[NG];
#pragma unroll
    for (int grp = 0; grp < NG; ++grp) {
        const float4 k = K4[kvbase + cols[grp] * CS4];
        p[grp] = fmaf(q.x, k.x, fmaf(q.y, k.y, fmaf(q.z, k.z, q.w * k.w)));
    }

    // 16-lane row sum: 4 pure-DPP stages (unchanged from R3).
#pragma unroll
    for (int grp = 0; grp < NG; ++grp) p[grp] = dpp_add<0xB1>(p[grp]);   // xor 1
#pragma unroll
    for (int grp = 0; grp < NG; ++grp) p[grp] = dpp_add<0x4E>(p[grp]);   // xor 2
#pragma unroll
    for (int grp = 0; grp < NG; ++grp) p[grp] = dpp_add<0x141>(p[grp]);  // half-mirror
#pragma unroll
    for (int grp = 0; grp < NG; ++grp) p[grp] = dpp_add<0x140>(p[grp]);  // mirror

    // Softmax across all 22 cols: local (per-slot) tree + 2 cross-row stages.
    const float scale = 0.125f;
#pragma unroll
    for (int grp = 0; grp < NG; ++grp)
        p[grp] = vld[grp] ? p[grp] * scale : -1e30f;

    float m = p[0];
#pragma unroll
    for (int grp = 1; grp < NG; ++grp) m = fmaxf(m, p[grp]);
    m = fmaxf(m, __shfl_xor(m, 16));
    m = fmaxf(m, __shfl_xor(m, 32));

    float s = 0.f;
#pragma unroll
    for (int grp = 0; grp < NG; ++grp) {
        p[grp] = __expf(p[grp] - m);       // masked: exp(-1e30 - m) -> 0
        s += p[grp];
    }
    s += __shfl_xor(s, 16);
    s += __shfl_xor(s, 32);
    const float inv = 1.0f / s;

    // O = sum_i w_i * V[col_i]; each lane covers (slot r, float4 g).
    float4 acc = make_float4(0.f, 0.f, 0.f, 0.f);
#pragma unroll
    for (int grp = 0; grp < NG; ++grp) {
        const float4 v = V4[kvbase + cols[grp] * CS4];
        acc.x = fmaf(p[grp], v.x, acc.x);
        acc.y = fmaf(p[grp], v.y, acc.y);
        acc.z = fmaf(p[grp], v.z, acc.z);
        acc.w = fmaf(p[grp], v.w, acc.w);
    }

    // Cross-row sum (rows hold disjoint column subsets of the same O[g]).
    acc.x += __shfl_xor(acc.x, 16);
    acc.y += __shfl_xor(acc.y, 16);
    acc.z += __shfl_xor(acc.z, 16);
    acc.w += __shfl_xor(acc.w, 16);
    acc.x += __shfl_xor(acc.x, 32);
    acc.y += __shfl_xor(acc.y, 32);
    acc.z += __shfl_xor(acc.z, 32);
    acc.w += __shfl_xor(acc.w, 32);

    if (r == 0)
        O4[qidx] = make_float4(acc.x * inv, acc.y * inv, acc.z * inv, acc.w * inv);
}

extern "C" void kernel_launch(void* const* d_in, const int* in_sizes, int n_in,
                              void* d_out, int out_size, void* d_ws, size_t ws_size,
                              hipStream_t stream) {
    const float4* Q = (const float4*)d_in[0];
    const float4* K = (const float4*)d_in[1];
    const float4* V = (const float4*)d_in[2];
    float4*       O = (float4*)d_out;

    // R9 probe: 3 idempotent launches. T_kernel_warm = (dur_us - 84.9) / 2.
    for (int rep = 0; rep < 3; ++rep)
        logsparse_attn<<<dim3(NBLK), dim3(WPB * 64), 0, stream>>>(Q, K, V, O);
}

// Round 3
// 88.038 us; speedup vs baseline: 1.3217x; 1.3217x over previous
//
#include <hip/hip_runtime.h>

// LogSparseAttention: B=2, L=S=2048, H=8, E=D=64, fp32.
// Mask (win_len=sub_len=2048, log_l=11):
//   l < 22  : causal prefix 0..l
//   l >= 22 : {l-10..l} U {l-10-2^j >= 0, j=0..10}  (<= 22 columns)
//
// R3: 4 rows/wave, 16 lanes/row, pure-DPP reduce.
// R4: XCD swizzle.  R5/R6 (reverted).  R7: 8-wave blocks.
// R8: head-per-XCD (neutral -> L2 capacity not the wall).
// R9: 3x-launch probe => T_kernel ~15.7 us warm; iteration = 44 us fill
//     (untouchable) + ~16-20 us kernel + ~20 us harness overhead.
// R10: LDS column staging. R7/R8 both push ~96 KB/block through the L1/TA
//     pipe (every wave re-fetches its own 22 columns; ~11 us/CU of vmem
//     issue = the wall). The 8-row union of columns is closed-form:
//     contiguous [l0-20, l0+7] (28 slots = window + near tails j<=3) plus
//     7 disjoint 8-col runs [l0-10-2^j .. l0-3-2^j], j=4..10 -> 84 slots.
//     Stage K+V (43 KB, 3 blocks/CU) with kv-major seg order so every
//     staging load is a contiguous 1 KB request; compute reads via
//     ds_read_b128 (separate pipe). Per-block wave-loads 104 -> 50.

constexpr int B = 2, L = 2048, S = 2048, H = 8, E = 64;
constexpr int LOGL = 11;                 // ceil(log2(2048))
constexpr int NG   = 6;                  // 6 groups x 4 col-slots = 24 >= 22
constexpr int WPB  = 8;                  // 8 waves = 8 consecutive l rows
constexpr int NBLK = B * L * H / WPB;    // 4096 blocks (head = blockIdx & 7)
constexpr int CONT = 28;                 // contiguous slots [l0-20, l0+7]
constexpr int NSLOT = CONT + 7 * 8;      // 84 columns per block
constexpr int CS4  = H * (E / 4);        // 128 float4 between columns

template<int CTRL>
__device__ __forceinline__ float dpp_add(float x) {
    int y = __builtin_amdgcn_update_dpp(0, __float_as_int(x), CTRL, 0xF, 0xF, true);
    return x + __int_as_float(y);
}

// Staged slot s -> global column (may be negative; caller clamps).
__device__ __forceinline__ int slot2col(int s, int l0) {
    if (s < CONT) return l0 - 20 + s;
    const int m = (s - CONT) >> 3;       // j = 4 + m
    const int i = (s - CONT) & 7;
    return l0 + i - 10 - (1 << (4 + m));
}

__global__ __launch_bounds__(WPB * 64)
void logsparse_attn(const float4* __restrict__ Q4,
                    const float4* __restrict__ K4,
                    const float4* __restrict__ V4,
                    float4* __restrict__ O4) {
    __shared__ float4 kv_lds[2][NSLOT * 16];   // [K/V][slot*16 + g] = 43 KB

    const int h    = blockIdx.x & 7;     // head == XCD (phys blk i -> XCD i%8)
    const int n    = blockIdx.x >> 3;    // 0..511: row-group, in-order per XCD
    const int t    = threadIdx.x;
    const int lane = t & 63;
    const int w    = t >> 6;             // wave in block: 0..7 == row i
    const int bl0  = n * WPB;            // first b*L + l of block
    const int l0   = bl0 & (L - 1);      // 2048 % 8 == 0 -> same b for block
    const int b    = bl0 >> 11;
    const int bl   = bl0 + w;
    const int l    = l0 + w;
    const int r    = lane >> 4;          // column slot within group: 0..3
    const int g    = lane & 15;          // float4 slot within 64-float row

    const int kvbase0 = (b * S * H + h) * (E / 4);

    // ---- Stage 84 columns of K and V into LDS (kv-major, contiguous 1 KB
    // wave-loads: slots 0..27 are consecutive cols; far runs are 8 long and
    // 4-aligned, so each 4-slot group is consecutive cols too). ----
    const int sg   = t & 15;             // lane within 256 B segment
    const int segg = t >> 4;             // 0..31 segment-groups per pass
#pragma unroll
    for (int pass = 0; pass < 6; ++pass) {
        const int seg = pass * 32 + segg;          // 0..191, active < 168
        if (seg < 2 * NSLOT) {
            const int kv = (seg >= NSLOT);
            const int s  = seg - (kv ? NSLOT : 0);
            int c = slot2col(s, l0);
            c = c < 0 ? 0 : c;                     // clamp: finite, weight==0
            const float4* __restrict__ src = kv ? V4 : K4;
            kv_lds[kv][(s << 4) + sg] = src[kvbase0 + c * CS4 + sg];
        }
    }

    // ---- Per-lane LDS slot for column slot idx = 4*grp + r ----
    int  slot[NG];
    bool vld[NG];
    if (l < 2 * LOGL) {                  // causal prefix: col idx itself
#pragma unroll
        for (int grp = 0; grp < NG; ++grp) {
            const int idx = 4 * grp + r;
            vld[grp]  = (idx <= l);
            slot[grp] = vld[grp] ? (idx + 20 - l0) : 0;
        }
    } else {
#pragma unroll
        for (int grp = 0; grp < NG; ++grp) {
            const int idx = 4 * grp + r;
            const int e   = idx - LOGL;                // j for tail slots
            const int sh  = e < 0 ? 0 : (e > 10 ? 10 : e);
            const bool isWin  = (idx <= 10);
            const bool isNear = (idx >= 11) && (idx <= 14);
            const bool isFar  = (idx >= 15) && (idx <= 21);
            const int sWin  = w + 10 + idx;            // col l-10+idx
            const int sNear = w + 10 - (1 << sh);      // col l-10-2^j, j=0..3
            const int sFar  = CONT + ((idx - 15) << 3) + w;
            const bool v = isWin || isNear ||
                           (isFar && (l - 10 - (1 << sh) >= 0));
            slot[grp] = v ? (isWin ? sWin : (isNear ? sNear : sFar)) : 0;
            vld[grp]  = v;
        }
    }

    const int qidx = (bl * H + h) * (E / 4) + g;
    const float4 q = Q4[qidx];

    __syncthreads();

    // ---- Scores from LDS ----
    float p[NG];
#pragma unroll
    for (int grp = 0; grp < NG; ++grp) {
        const float4 k = kv_lds[0][(slot[grp] << 4) + g];
        p[grp] = fmaf(q.x, k.x, fmaf(q.y, k.y, fmaf(q.z, k.z, q.w * k.w)));
    }

    // 16-lane row sum: 4 pure-DPP stages.
#pragma unroll
    for (int grp = 0; grp < NG; ++grp) p[grp] = dpp_add<0xB1>(p[grp]);   // xor 1
#pragma unroll
    for (int grp = 0; grp < NG; ++grp) p[grp] = dpp_add<0x4E>(p[grp]);   // xor 2
#pragma unroll
    for (int grp = 0; grp < NG; ++grp) p[grp] = dpp_add<0x141>(p[grp]);  // half-mirror
#pragma unroll
    for (int grp = 0; grp < NG; ++grp) p[grp] = dpp_add<0x140>(p[grp]);  // mirror

    // ---- Softmax over 22 cols: per-slot tree + 2 cross-row stages ----
    const float scale = 0.125f;
#pragma unroll
    for (int grp = 0; grp < NG; ++grp)
        p[grp] = vld[grp] ? p[grp] * scale : -1e30f;

    float m = p[0];
#pragma unroll
    for (int grp = 1; grp < NG; ++grp) m = fmaxf(m, p[grp]);
    m = fmaxf(m, __shfl_xor(m, 16));
    m = fmaxf(m, __shfl_xor(m, 32));

    float s = 0.f;
#pragma unroll
    for (int grp = 0; grp < NG; ++grp) {
        p[grp] = __expf(p[grp] - m);     // masked: exp(-1e30 - m) -> 0
        s += p[grp];
    }
    s += __shfl_xor(s, 16);
    s += __shfl_xor(s, 32);
    const float inv = 1.0f / s;

    // ---- O = sum_i w_i * V[col_i], V from LDS ----
    float4 acc = make_float4(0.f, 0.f, 0.f, 0.f);
#pragma unroll
    for (int grp = 0; grp < NG; ++grp) {
        const float4 v = kv_lds[1][(slot[grp] << 4) + g];
        acc.x = fmaf(p[grp], v.x, acc.x);
        acc.y = fmaf(p[grp], v.y, acc.y);
        acc.z = fmaf(p[grp], v.z, acc.z);
        acc.w = fmaf(p[grp], v.w, acc.w);
    }

    // Cross-row sum (r-slots hold disjoint column subsets of the same O[g]).
    acc.x += __shfl_xor(acc.x, 16);
    acc.y += __shfl_xor(acc.y, 16);
    acc.z += __shfl_xor(acc.z, 16);
    acc.w += __shfl_xor(acc.w, 16);
    acc.x += __shfl_xor(acc.x, 32);
    acc.y += __shfl_xor(acc.y, 32);
    acc.z += __shfl_xor(acc.z, 32);
    acc.w += __shfl_xor(acc.w, 32);

    if (r == 0)
        O4[qidx] = make_float4(acc.x * inv, acc.y * inv, acc.z * inv, acc.w * inv);
}

extern "C" void kernel_launch(void* const* d_in, const int* in_sizes, int n_in,
                              void* d_out, int out_size, void* d_ws, size_t ws_size,
                              hipStream_t stream) {
    const float4* Q = (const float4*)d_in[0];
    const float4* K = (const float4*)d_in[1];
    const float4* V = (const float4*)d_in[2];
    float4*       O = (float4*)d_out;

    logsparse_attn<<<dim3(NBLK), dim3(WPB * 64), 0, stream>>>(Q, K, V, O);
}

// Round 4
// 85.732 us; speedup vs baseline: 1.3572x; 1.0269x over previous
//
#include <hip/hip_runtime.h>

// LogSparseAttention: B=2, L=S=2048, H=8, E=D=64, fp32.
// Mask (win_len=sub_len=2048, log_l=11):
//   l < 22  : causal prefix 0..l
//   l >= 22 : {l-10..l} U {l-10-2^j >= 0, j=0..10}  (<= 22 columns)
//
// R3: 4 rows/wave, 16 lanes/row, pure-DPP reduce.   R4: XCD swizzle.
// R5/R6 (reverted).  R7: 8-wave blocks.  R8: head-per-XCD (neutral).
// R9: probe => T_kernel ~15.7 us warm of 84.9 dur (44 us fill + ~20 us
//     harness overhead are untouchable).
// R10: LDS staging of the 8-row column union (REGRESSED +3 us). Diagnosed
//     flaws: 43 KB LDS -> 24 waves/CU; [slot][g] stride 256 B -> 4-way
//     bank conflict on every compute ds_read_b128; 8-wave 6-pass staging.
// R11: clean retest of the traffic-cut theory with all three flaws fixed:
//     16-row blocks (1024 thr). Union = contiguous [l0-20, l0+15] (36) +
//     7 far runs of 16 ([l0-10-2^j .. l0+5-2^j], j=4..10) = 148 slots;
//     K+V = 75.8 KB -> 2 blocks/CU = 32 waves/CU (full occupancy).
//     XOR swizzle g ^= (slot&3)<<2 kills the 4-way conflict at zero LDS
//     cost (write side applies the same involution). Staging = 5 passes
//     x 64 segments by 16 waves, contiguous 1 KB wave-loads. Per-CU
//     global traffic ~1.6 MB -> ~0.7 MB; per-wave vmem 13 -> ~6 loads.

constexpr int B = 2, L = 2048, S = 2048, H = 8, E = 64;
constexpr int LOGL = 11;                 // ceil(log2(2048))
constexpr int NG   = 6;                  // 6 groups x 4 col-slots = 24 >= 22
constexpr int RT   = 16;                 // rows (waves) per block
constexpr int NBLK = B * L * H / RT;     // 2048 blocks (head = blockIdx & 7)
constexpr int CONT = 36;                 // contiguous slots [l0-20, l0+15]
constexpr int NSLOT = CONT + 7 * RT;     // 148 columns per block
constexpr int CS4  = H * (E / 4);        // 128 float4 between columns

template<int CTRL>
__device__ __forceinline__ float dpp_add(float x) {
    int y = __builtin_amdgcn_update_dpp(0, __float_as_int(x), CTRL, 0xF, 0xF, true);
    return x + __int_as_float(y);
}

// Staged slot s -> global column (may be negative; caller clamps; clamped
// slots are only read with weight 0 or never read).
__device__ __forceinline__ int slot2col(int s, int l0) {
    if (s < CONT) return l0 - 20 + s;
    const int m = (s - CONT) >> 4;       // j = 4 + m
    const int i = (s - CONT) & 15;       // row offset within run
    return l0 + i - 10 - (1 << (4 + m));
}

__global__ __launch_bounds__(RT * 64, 8)
void logsparse_attn(const float4* __restrict__ Q4,
                    const float4* __restrict__ K4,
                    const float4* __restrict__ V4,
                    float4* __restrict__ O4) {
    __shared__ float4 kv_lds[2][NSLOT * 16];   // 75,776 B -> 2 blocks/CU

    const int h    = blockIdx.x & 7;     // head == XCD (phys blk i -> XCD i%8)
    const int n    = blockIdx.x >> 3;    // 0..255: row-group, in-order per XCD
    const int t    = threadIdx.x;
    const int lane = t & 63;
    const int w    = t >> 6;             // wave in block == row i: 0..15
    const int bl0  = n * RT;             // first b*L + l of block
    const int l0   = bl0 & (L - 1);      // 2048 % 16 == 0 -> same b for block
    const int b    = bl0 >> 11;
    const int bl   = bl0 + w;
    const int l    = l0 + w;
    const int r    = lane >> 4;          // column slot within group: 0..3
    const int g    = lane & 15;          // float4 slot within 64-float row

    const int kvbase0 = (b * S * H + h) * (E / 4);

    // ---- Stage 148 columns of K and V into LDS. 296 segments of 256 B;
    // 64 segments/pass (16 waves x 4), 5 passes. Segments are 4-aligned
    // groups of consecutive columns -> each wave-load is 1 KB contiguous.
    // XOR involution on the float4 index de-conflicts later ds_reads. ----
    const int sg   = t & 15;             // lane within 256 B segment
    const int segg = t >> 4;             // 0..63 segment-groups per pass
#pragma unroll
    for (int pass = 0; pass < 5; ++pass) {
        const int seg = pass * 64 + segg;          // 0..319, active < 296
        if (seg < 2 * NSLOT) {
            const int kv = (seg >= NSLOT);
            const int s  = seg - (kv ? NSLOT : 0);
            int c = slot2col(s, l0);
            c = c < 0 ? 0 : c;                     // clamp: finite, weight==0
            const float4* __restrict__ src = kv ? V4 : K4;
            kv_lds[kv][(s << 4) + (sg ^ ((s & 3) << 2))] =
                src[kvbase0 + c * CS4 + sg];
        }
    }

    // ---- Per-lane LDS slot for column slot idx = 4*grp + r ----
    int  slot[NG];
    bool vld[NG];
    if (l < 2 * LOGL) {                  // causal prefix rows (blocks l0=0,16)
#pragma unroll
        for (int grp = 0; grp < NG; ++grp) {
            const int idx = 4 * grp + r;
            vld[grp]  = (idx <= l);
            slot[grp] = vld[grp] ? (idx + 20 - l0) : 0;   // col idx itself
        }
    } else {
#pragma unroll
        for (int grp = 0; grp < NG; ++grp) {
            const int idx = 4 * grp + r;
            const int e   = idx - LOGL;                // tail j for idx>=11
            const int sh  = e < 0 ? 0 : (e > 10 ? 10 : e);
            const bool isWin  = (idx <= 10);
            const bool isNear = (idx >= 11) && (idx <= 14);
            const bool isFar  = (idx >= 15) && (idx <= 21);
            const int sWin  = w + 10 + idx;            // col l-10+idx
            const int sNear = w + 10 - (1 << sh);      // col l-10-2^j, j=0..3
            const int sFar  = CONT + ((idx - 15) << 4) + w;  // run j=idx-11
            const bool v = isWin || isNear ||
                           (isFar && (l - 10 - (1 << sh) >= 0));
            slot[grp] = v ? (isWin ? sWin : (isNear ? sNear : sFar)) : 0;
            vld[grp]  = v;
        }
    }

    const int qidx = (bl * H + h) * (E / 4) + g;
    const float4 q = Q4[qidx];

    __syncthreads();

    // ---- Scores from LDS (swizzled read; 4 slots/group hit 4 distinct
    // bank quartets -> conflict-free) ----
    float p[NG];
#pragma unroll
    for (int grp = 0; grp < NG; ++grp) {
        const float4 k = kv_lds[0][(slot[grp] << 4) + (g ^ ((slot[grp] & 3) << 2))];
        p[grp] = fmaf(q.x, k.x, fmaf(q.y, k.y, fmaf(q.z, k.z, q.w * k.w)));
    }

    // 16-lane row sum: 4 pure-DPP stages.
#pragma unroll
    for (int grp = 0; grp < NG; ++grp) p[grp] = dpp_add<0xB1>(p[grp]);   // xor 1
#pragma unroll
    for (int grp = 0; grp < NG; ++grp) p[grp] = dpp_add<0x4E>(p[grp]);   // xor 2
#pragma unroll
    for (int grp = 0; grp < NG; ++grp) p[grp] = dpp_add<0x141>(p[grp]);  // half-mirror
#pragma unroll
    for (int grp = 0; grp < NG; ++grp) p[grp] = dpp_add<0x140>(p[grp]);  // mirror

    // ---- Softmax over 22 cols: per-slot tree + 2 cross-row stages ----
    const float scale = 0.125f;
#pragma unroll
    for (int grp = 0; grp < NG; ++grp)
        p[grp] = vld[grp] ? p[grp] * scale : -1e30f;

    float m = p[0];
#pragma unroll
    for (int grp = 1; grp < NG; ++grp) m = fmaxf(m, p[grp]);
    m = fmaxf(m, __shfl_xor(m, 16));
    m = fmaxf(m, __shfl_xor(m, 32));

    float s = 0.f;
#pragma unroll
    for (int grp = 0; grp < NG; ++grp) {
        p[grp] = __expf(p[grp] - m);     // masked: exp(-1e30 - m) -> 0
        s += p[grp];
    }
    s += __shfl_xor(s, 16);
    s += __shfl_xor(s, 32);
    const float inv = 1.0f / s;

    // ---- O = sum_i w_i * V[col_i], V from LDS (same swizzle) ----
    float4 acc = make_float4(0.f, 0.f, 0.f, 0.f);
#pragma unroll
    for (int grp = 0; grp < NG; ++grp) {
        const float4 v = kv_lds[1][(slot[grp] << 4) + (g ^ ((slot[grp] & 3) << 2))];
        acc.x = fmaf(p[grp], v.x, acc.x);
        acc.y = fmaf(p[grp], v.y, acc.y);
        acc.z = fmaf(p[grp], v.z, acc.z);
        acc.w = fmaf(p[grp], v.w, acc.w);
    }

    // Cross-row sum (r-slots hold disjoint column subsets of the same O[g]).
    acc.x += __shfl_xor(acc.x, 16);
    acc.y += __shfl_xor(acc.y, 16);
    acc.z += __shfl_xor(acc.z, 16);
    acc.w += __shfl_xor(acc.w, 16);
    acc.x += __shfl_xor(acc.x, 32);
    acc.y += __shfl_xor(acc.y, 32);
    acc.z += __shfl_xor(acc.z, 32);
    acc.w += __shfl_xor(acc.w, 32);

    if (r == 0)
        O4[qidx] = make_float4(acc.x * inv, acc.y * inv, acc.z * inv, acc.w * inv);
}

extern "C" void kernel_launch(void* const* d_in, const int* in_sizes, int n_in,
                              void* d_out, int out_size, void* d_ws, size_t ws_size,
                              hipStream_t stream) {
    const float4* Q = (const float4*)d_in[0];
    const float4* K = (const float4*)d_in[1];
    const float4* V = (const float4*)d_in[2];
    float4*       O = (float4*)d_out;

    logsparse_attn<<<dim3(NBLK), dim3(RT * 64), 0, stream>>>(Q, K, V, O);
}

// Round 5
// 84.919 us; speedup vs baseline: 1.3702x; 1.0096x over previous
//
#include <hip/hip_runtime.h>

// LogSparseAttention: B=2, L=S=2048, H=8, E=D=64, fp32.
// Mask (win_len=sub_len=2048, log_l=11):
//   l < 22  : causal prefix 0..l
//   l >= 22 : {l-10..l} U {l-10-2^j >= 0, j=0..10}  (<= 22 columns)
//
// R3: 4 rows/wave (4 heads), 16 lanes/row, pure-DPP reduce, SGPR cols.
// R4: XCD-aware swizzle (contiguous l-slab per XCD).
// R5 (reverted): bf16 packing — bytes not the wall.
// R6 (reverted): register mega-buffers / 256-VGPR — MLP not the wall.
// R7: 8-wave blocks (4 consecutive l x both head groups) for L1 locality.
//     BEST MEASURED: 83.7 us.
// R8: head-per-XCD partitioning — neutral (84.9).
// R9: 3x-launch probe — kernel ~15.7 us warm; dur = 44 us poison fill +
//     ~25 us harness small-dispatch overhead + kernel.
// R10: LDS staging of 8-row column union — regressed (88.0; 24 waves/CU +
//      4-way LDS bank conflict, confounded test).
// R11: clean staging test (16-row blocks, 75.8 KB LDS, 2 blocks/CU full
//      occupancy, XOR-swizzled conflict-free reads, coalesced 1 KB staging,
//      ~6 vmem loads/wave) — still 85.7. CONCLUSION: kernel time is
//      structure-independent; floor = compulsory cold re-stream of Q/K/V
//      (~50 MB behind the cache-wiping 256 MiB fill, ~8 us) + launch ramp.
//      Traffic, footprint, occupancy, conflict levers all exhausted.
// R12: REVERT to R7 (best measured). Session at harness/compulsory floor.

constexpr int B = 2, L = 2048, S = 2048, H = 8, E = 64;
constexpr int LOGL = 11;
constexpr int MAXC = 2 * LOGL;           // 22
constexpr int LT   = 4;                  // l-tile per block
constexpr int WPB  = 8;                  // waves per block (4 l x 2 head-grp)
constexpr int NBLK = B * L / LT;         // 1024

template<int CTRL>
__device__ __forceinline__ float dpp_add(float x) {
    int y = __builtin_amdgcn_update_dpp(0, __float_as_int(x), CTRL, 0xF, 0xF, true);
    return x + __int_as_float(y);
}

__global__ __launch_bounds__(WPB * 64)
void logsparse_attn(const float4* __restrict__ Q4,
                    const float4* __restrict__ K4,
                    const float4* __restrict__ V4,
                    float4* __restrict__ O4) {
    // XCD-aware swizzle: phys block i runs on XCD i%8; XCD x gets the
    // contiguous logical range [x*NBLK/8, (x+1)*NBLK/8)  (512-l slab).
    const int logical = (blockIdx.x & 7) * (NBLK / 8) + (blockIdx.x >> 3);

    const int lane = threadIdx.x & 63;
    const int w    = threadIdx.x >> 6;      // wave in block: 0..7
    const int dl   = w >> 1;                // l offset within tile: 0..3
    const int hg   = (w & 1) * 4;           // head group: 0 or 4
    const int bl   = logical * LT + dl;     // b*L + l
    const int l    = bl & (L - 1);
    const int b    = bl >> 11;              // L = 2048
    const int r    = lane >> 4;             // head within wave: 0..3
    const int g    = lane & 15;             // float4 slot within row: 0..15
    const int h    = hg + r;

    // Active-column list — identical for the 4 heads (depends only on l).
    int  cols[MAXC];
    bool val[MAXC];
    if (l < 2 * LOGL) {                     // full causal prefix
#pragma unroll
        for (int i = 0; i < MAXC; ++i) {
            val[i]  = (i <= l);
            cols[i] = val[i] ? i : 0;
        }
    } else {
#pragma unroll
        for (int j = 0; j < LOGL; ++j) {    // l-10 .. l
            cols[j] = l - (LOGL - 1) + j;
            val[j]  = true;
        }
#pragma unroll
        for (int j = 0; j < LOGL; ++j) {    // l-10-2^j
            int c = l - (LOGL - 1) - (1 << j);
            val[LOGL + j]  = (c >= 0);
            cols[LOGL + j] = (c >= 0) ? c : 0;
        }
    }
#pragma unroll
    for (int i = 0; i < MAXC; ++i)
        cols[i] = __builtin_amdgcn_readfirstlane(cols[i]);   // wave-uniform -> SGPR

    const int qidx   = (bl * H + h) * (E / 4) + g;
    const int kvlane = (b * S * H + h) * (E / 4) + g;
    constexpr int CSTRIDE4 = H * (E / 4);   // 128 float4 per column

    const float4 q = Q4[qidx];

    // Partial dot products: 22 coalesced dwordx4 loads (1 KB/wave/instr).
    float p[MAXC];
#pragma unroll
    for (int i = 0; i < MAXC; ++i) {
        const float4 k = K4[kvlane + cols[i] * CSTRIDE4];
        p[i] = fmaf(q.x, k.x, fmaf(q.y, k.y, fmaf(q.z, k.z, q.w * k.w)));
    }

    // 16-lane-row sum: 4 pure-DPP stages (no LDS pipe).
#pragma unroll
    for (int i = 0; i < MAXC; ++i) p[i] = dpp_add<0xB1>(p[i]);   // xor 1
#pragma unroll
    for (int i = 0; i < MAXC; ++i) p[i] = dpp_add<0x4E>(p[i]);   // xor 2
#pragma unroll
    for (int i = 0; i < MAXC; ++i) p[i] = dpp_add<0x141>(p[i]);  // half-mirror
#pragma unroll
    for (int i = 0; i < MAXC; ++i) p[i] = dpp_add<0x140>(p[i]);  // mirror

    // Softmax; masked -> -1e30 -> exp underflows to 0 (matches -1e9*scale).
    const float scale = 0.125f;
#pragma unroll
    for (int i = 0; i < MAXC; ++i)
        p[i] = val[i] ? p[i] * scale : -1e30f;

    float mx[MAXC];
#pragma unroll
    for (int i = 0; i < MAXC; ++i) mx[i] = p[i];
#pragma unroll
    for (int s = 1; s < MAXC; s <<= 1)
#pragma unroll
        for (int i = 0; i + s < MAXC; i += 2 * s)
            mx[i] = fmaxf(mx[i], mx[i + s]);
    const float m = mx[0];

#pragma unroll
    for (int i = 0; i < MAXC; ++i)
        p[i] = __expf(p[i] - m);

    float sm[MAXC];
#pragma unroll
    for (int i = 0; i < MAXC; ++i) sm[i] = p[i];
#pragma unroll
    for (int s = 1; s < MAXC; s <<= 1)
#pragma unroll
        for (int i = 0; i + s < MAXC; i += 2 * s)
            sm[i] += sm[i + s];
    const float inv = 1.0f / sm[0];

    // O = sum_i w_i * V[col_i]
    float4 acc = make_float4(0.f, 0.f, 0.f, 0.f);
#pragma unroll
    for (int i = 0; i < MAXC; ++i) {
        const float4 v = V4[kvlane + cols[i] * CSTRIDE4];
        acc.x = fmaf(p[i], v.x, acc.x);
        acc.y = fmaf(p[i], v.y, acc.y);
        acc.z = fmaf(p[i], v.z, acc.z);
        acc.w = fmaf(p[i], v.w, acc.w);
    }

    O4[qidx] = make_float4(acc.x * inv, acc.y * inv, acc.z * inv, acc.w * inv);
}

extern "C" void kernel_launch(void* const* d_in, const int* in_sizes, int n_in,
                              void* d_out, int out_size, void* d_ws, size_t ws_size,
                              hipStream_t stream) {
    const float4* Q = (const float4*)d_in[0];
    const float4* K = (const float4*)d_in[1];
    const float4* V = (const float4*)d_in[2];
    float4*       O = (float4*)d_out;

    logsparse_attn<<<dim3(NBLK), dim3(WPB * 64), 0, stream>>>(Q, K, V, O);
}